// Round 18
// baseline (249.194 us; speedup 1.0000x reference)
//
#include <hip/hip_runtime.h>
#include <hip/hip_bf16.h>
#include <cstddef>
#include <cstdint>

#define CAP 32
#define LEAK 0.01f

typedef __attribute__((ext_vector_type(8))) short short8v;
typedef __attribute__((ext_vector_type(4))) float float4v;

__device__ __forceinline__ unsigned short f2bf(float f) {
    uint32_t u = __float_as_uint(f);
    uint32_t r = (u + 0x7FFFu + ((u >> 16) & 1u)) >> 16;   // RNE
    return (unsigned short)r;
}
__device__ __forceinline__ float bf2f(unsigned short s) {
    return __uint_as_float(((uint32_t)s) << 16);
}

// ---------------------------------------------------------------------------
// prep: one kernel, block-ranges (overlap latency-bound edge atomics with the
// BW-bound convert and tiny pack/fold/scan work). All fold work is plain fp32
// dot products (low VGPR; r16 lesson). Scatter: 8 edges/thread (more MLP).
// ---------------------------------------------------------------------------
__global__ __launch_bounds__(256) void prep(const int* __restrict__ ei, int E_,
                                            int* __restrict__ cnt,
                                            int* __restrict__ bucket,
                                            const float* __restrict__ node_attr,
                                            unsigned short* __restrict__ bx, int Nn,
                                            const float* __restrict__ enc_W,
                                            const float* __restrict__ gcn_W,
                                            const float* __restrict__ rw1,
                                            const float* __restrict__ rw2,
                                            const float* __restrict__ sw1,
                                            const float* __restrict__ sw2,
                                            const float* __restrict__ enc_b,
                                            const float* __restrict__ gcn_b,
                                            const float* __restrict__ rb1,
                                            const float* __restrict__ sb1,
                                            unsigned short* __restrict__ wpack,
                                            float* __restrict__ fold32,
                                            float* __restrict__ fbias,
                                            const int* __restrict__ na,
                                            int* __restrict__ goff, int G_,
                                            int NB_EDGE, int NB_CVT) {
    const int b = blockIdx.x;
    const int tid = threadIdx.x;

    if (b < NB_EDGE) {
        int e = (b * 256 + tid) * 8;
        if (e >= E_) return;
        if (e + 8 <= E_) {
            int4 da = *(const int4*)&ei[e];
            int4 db = *(const int4*)&ei[e + 4];
            int4 sa = *(const int4*)&ei[(size_t)E_ + e];
            int4 sb = *(const int4*)&ei[(size_t)E_ + e + 4];
            int p0 = atomicAdd(&cnt[da.x], 1);
            int p1 = atomicAdd(&cnt[da.y], 1);
            int p2 = atomicAdd(&cnt[da.z], 1);
            int p3 = atomicAdd(&cnt[da.w], 1);
            int p4 = atomicAdd(&cnt[db.x], 1);
            int p5 = atomicAdd(&cnt[db.y], 1);
            int p6 = atomicAdd(&cnt[db.z], 1);
            int p7 = atomicAdd(&cnt[db.w], 1);
            if (p0 < CAP) bucket[(size_t)da.x * CAP + p0] = sa.x;
            if (p1 < CAP) bucket[(size_t)da.y * CAP + p1] = sa.y;
            if (p2 < CAP) bucket[(size_t)da.z * CAP + p2] = sa.z;
            if (p3 < CAP) bucket[(size_t)da.w * CAP + p3] = sa.w;
            if (p4 < CAP) bucket[(size_t)db.x * CAP + p4] = sb.x;
            if (p5 < CAP) bucket[(size_t)db.y * CAP + p5] = sb.y;
            if (p6 < CAP) bucket[(size_t)db.z * CAP + p6] = sb.z;
            if (p7 < CAP) bucket[(size_t)db.w * CAP + p7] = sb.w;
        } else {
            for (; e < E_; ++e) {
                int d = ei[e], s = ei[(size_t)E_ + e];
                int p = atomicAdd(&cnt[d], 1);
                if (p < CAP) bucket[(size_t)d * CAP + p] = s;
            }
        }
        return;
    }
    if (b < NB_EDGE + NB_CVT) {
        size_t i8 = ((size_t)(b - NB_EDGE) * 256 + tid) * 8;
        if (i8 < (size_t)Nn * 128) {
            const float* ap = node_attr + i8;
            float4v p = *(const float4v*)ap;
            float4v q = *(const float4v*)(ap + 4);
            short8v v;
            v[0] = (short)f2bf(p[0]); v[1] = (short)f2bf(p[1]);
            v[2] = (short)f2bf(p[2]); v[3] = (short)f2bf(p[3]);
            v[4] = (short)f2bf(q[0]); v[5] = (short)f2bf(q[1]);
            v[6] = (short)f2bf(q[2]); v[7] = (short)f2bf(q[3]);
            *(short8v*)(bx + i8) = v;
        }
        return;
    }
    if (b < NB_EDGE + NB_CVT + 16) {
        int pb = b - (NB_EDGE + NB_CVT);
        int m = (pb < 8) ? 6 : 8;
        int idx = (pb & 7) * 256 + tid;
        const float* W = (m == 6) ? rw2 : sw2;
        int n = idx & 127;
        int fg = (idx >> 7) & 3;
        int kc = idx >> 9;
        short8v v;
#pragma unroll
        for (int j = 0; j < 8; ++j)
            v[j] = (short)f2bf(W[(size_t)(kc * 32 + fg * 8 + j) * 128 + n]);
        *(short8v*)(wpack + (size_t)m * 16384 + (size_t)idx * 8) = v;
        return;
    }
    int fb = b - (NB_EDGE + NB_CVT + 16);
    if (fb < 256) {
        // ---- fold level 1: 4 independent 128x128 fp32 products ----
        int which = fb >> 6;                 // 0:A=We@W1 1:B=W2@W3 2:C=W4@rW1 3:D=W4@sW1
        int r = (fb & 63) * 2 + (tid >> 7);  // output row
        int n = tid & 127;                   // output col
        const float* L;
        const float* R;
        switch (which) {
            case 0: L = enc_W;                       R = gcn_W;                 break;
            case 1: L = gcn_W + (size_t)1 * 16384;   R = gcn_W + (size_t)2 * 16384; break;
            case 2: L = gcn_W + (size_t)3 * 16384;   R = rw1;                   break;
            default: L = gcn_W + (size_t)3 * 16384;  R = sw1;                   break;
        }
        float acc = 0.f;
#pragma unroll 8
        for (int k = 0; k < 128; ++k)
            acc = fmaf(L[(size_t)r * 128 + k], R[(size_t)k * 128 + n], acc);
        fold32[(size_t)which * 16384 + (size_t)r * 128 + n] = acc;
        return;
    }
    fb -= 256;
    if (fb == 0) {
        // ---- beta chain + folded biases (fp32 exact) ----
        __shared__ float betaL[128];
        if (tid < 128) betaL[tid] = enc_b[tid];
        __syncthreads();
        for (int l = 0; l < 4; ++l) {
            const float* Wl = gcn_W + (size_t)l * 16384;
            float acc = 0.f;
            if (tid < 128) {
                acc = gcn_b[l * 128 + tid];
                for (int k = 0; k < 128; ++k)
                    acc = fmaf(betaL[k], Wl[(size_t)k * 128 + tid], acc);
            }
            __syncthreads();
            if (tid < 128) betaL[tid] = acc;
            __syncthreads();
        }
        if (tid < 128) {
            float a1 = rb1[tid], a2 = sb1[tid];
            for (int k = 0; k < 128; ++k) {
                float bk = betaL[k];
                a1 = fmaf(bk, rw1[(size_t)k * 128 + tid], a1);
                a2 = fmaf(bk, sw1[(size_t)k * 128 + tid], a2);
            }
            fbias[128 + tid] = a1;
            fbias[256 + tid] = a2;
        }
        return;
    }
    if (fb == 1) {
        // ---- exclusive scan num_atoms -> goff (G <= 1024) ----
        __shared__ int sh[256];
        int base = tid * 4;
        int v0 = (base + 0 < G_) ? na[base + 0] : 0;
        int v1 = (base + 1 < G_) ? na[base + 1] : 0;
        int v2 = (base + 2 < G_) ? na[base + 2] : 0;
        int v3 = (base + 3 < G_) ? na[base + 3] : 0;
        int s = v0 + v1 + v2 + v3;
        sh[tid] = s;
        __syncthreads();
        for (int ofs = 1; ofs < 256; ofs <<= 1) {
            int u = (tid >= ofs) ? sh[tid - ofs] : 0;
            __syncthreads();
            sh[tid] += u;
            __syncthreads();
        }
        int run = sh[tid] - s;
        if (tid == 0) goff[0] = 0;
        run += v0; if (base + 0 < G_) goff[base + 1] = run;
        run += v1; if (base + 1 < G_) goff[base + 2] = run;
        run += v2; if (base + 2 < G_) goff[base + 3] = run;
        run += v3; if (base + 3 < G_) goff[base + 4] = run;
    }
}

// ---------------------------------------------------------------------------
// accumulate 8 bf16 (uint4) into 8 f32, predicated by m
// ---------------------------------------------------------------------------
__device__ __forceinline__ void acc8(float a[8], uint4 v, float m) {
    a[0] = fmaf(m, bf2f((unsigned short)(v.x & 0xffff)), a[0]);
    a[1] = fmaf(m, bf2f((unsigned short)(v.x >> 16)), a[1]);
    a[2] = fmaf(m, bf2f((unsigned short)(v.y & 0xffff)), a[2]);
    a[3] = fmaf(m, bf2f((unsigned short)(v.y >> 16)), a[3]);
    a[4] = fmaf(m, bf2f((unsigned short)(v.z & 0xffff)), a[4]);
    a[5] = fmaf(m, bf2f((unsigned short)(v.z >> 16)), a[5]);
    a[6] = fmaf(m, bf2f((unsigned short)(v.w & 0xffff)), a[6]);
    a[7] = fmaf(m, bf2f((unsigned short)(v.w >> 16)), a[7]);
}

// issue the 4 gather loads for round jb of this group's node into V[0..3]
__device__ __forceinline__ void issue4(const char* __restrict__ xb, int2 prep_,
                                       int gl, int l16, int Nn, int jb, uint4 V[4]) {
    const int sl = gl + (jb >> 1);
    int s0 = __shfl(prep_.x, sl);
    int s1 = __shfl(prep_.y, sl);
    int s2 = __shfl(prep_.x, sl + 1);
    int s3 = __shfl(prep_.y, sl + 1);
    s0 = min(max(s0, 0), Nn - 1);   // masked slots hold poison -> clamp to hot row
    s1 = min(max(s1, 0), Nn - 1);
    s2 = min(max(s2, 0), Nn - 1);
    s3 = min(max(s3, 0), Nn - 1);
    V[0] = *(const uint4*)(xb + (size_t)s0 * 256 + l16 * 16);
    V[1] = *(const uint4*)(xb + (size_t)s1 * 256 + l16 * 16);
    V[2] = *(const uint4*)(xb + (size_t)s2 * 256 + l16 * 16);
    V[3] = *(const uint4*)(xb + (size_t)s3 * 256 + l16 * 16);
}

__device__ __forceinline__ void consume4(float a[8], const uint4 V[4], int jb, int d) {
    acc8(a, V[0], (jb + 0 < d) ? 1.f : 0.f);
    acc8(a, V[1], (jb + 1 < d) ? 1.f : 0.f);
    acc8(a, V[2], (jb + 2 < d) ? 1.f : 0.f);
    acc8(a, V[3], (jb + 3 < d) ? 1.f : 0.f);
}

// ---------------------------------------------------------------------------
// Aggregate-only pass (r12-verified gather structure). All 4 GCN layers are
// pure aggregation (weights folded into the gate via linearity).
// FM = fold-tail mode for blocks >= aggGrid (hidden fold work, low VGPR):
//   FM=0 none; FM=1 E=A@B (fp32, 64 blocks); FM=2 slots 9/10 = E@{C,D}
//   (bf16 fragpack, 128 blocks).
// ---------------------------------------------------------------------------
template <int FM>
__global__ __launch_bounds__(256, 4) void agg_pass(const unsigned short* __restrict__ x,
                                                   const int* __restrict__ bucket,
                                                   const int* __restrict__ cnt,
                                                   unsigned short* __restrict__ xout,
                                                   int Nn, int aggGrid,
                                                   float* __restrict__ fold32,
                                                   unsigned short* __restrict__ wpack) {
    if (FM != 0 && (int)blockIdx.x >= aggGrid) {
        const int tid = threadIdx.x;
        const int e = blockIdx.x - aggGrid;
        if (FM == 1) {
            // E = A @ B
            int r = e * 2 + (tid >> 7), n = tid & 127;
            const float* A = fold32;
            const float* B = fold32 + 16384;
            float acc = 0.f;
#pragma unroll 8
            for (int k = 0; k < 128; ++k)
                acc = fmaf(A[(size_t)r * 128 + k], B[(size_t)k * 128 + n], acc);
            fold32[65536 + (size_t)r * 128 + n] = acc;
        } else {
            // slot9 = E @ C ; slot10 = E @ D  (bf16 fragpack layout)
            int panel = e >> 6;
            int r = (e & 63) * 2 + (tid >> 7), n = tid & 127;
            const float* Ep = fold32 + 65536;
            const float* CD = fold32 + (size_t)(2 + panel) * 16384;
            float acc = 0.f;
#pragma unroll 8
            for (int k = 0; k < 128; ++k)
                acc = fmaf(Ep[(size_t)r * 128 + k], CD[(size_t)k * 128 + n], acc);
            int kc = r >> 5, fg2 = (r >> 3) & 3, j = r & 7;
            wpack[(size_t)(9 + panel) * 16384 +
                  (size_t)(((kc * 4 + fg2) * 128 + n) * 8 + j)] = f2bf(acc);
        }
        return;
    }

    const int tid = threadIdx.x;
    const int lane = tid & 63;
    const int w = tid >> 6;
    const int row0 = blockIdx.x * 64;
    const int l16 = lane & 15;
    const int g = lane >> 4;          // 16-lane group 0..3
    const int gl = lane & 48;         // g*16
    const char* xb = (const char*)x;

    // ---- up-front prefetch: cnt (1 load), own rows (4), neighbor idx (4) ----
    int cfull = 0;
    if (lane < 16) {
        int gn = row0 + w * 16 + lane;
        if (gn >= Nn) gn = Nn - 1;
        cfull = cnt[gn];
    }
    uint4 own[4];
    int2 pre[4];      // pass p: slots 2*l16, 2*l16+1 of node 4p+g (covers 0..31)
#pragma unroll
    for (int p = 0; p < 4; ++p) {
        int gn = row0 + w * 16 + p * 4 + g;
        if (gn >= Nn) gn = Nn - 1;
        own[p] = *(const uint4*)(xb + (size_t)gn * 256 + l16 * 16);
        pre[p] = *(const int2*)&bucket[(size_t)gn * CAP + 2 * l16];
    }

    // ---- 4 gather passes, fully unrolled (static own/pre indexing) ----
#pragma unroll
    for (int p = 0; p < 4; ++p) {
        const int n = p * 4 + g;          // node within wave tile, 0..15
        const int r = w * 16 + n;
        const int dfull = __shfl(cfull, n);
        const float id = 1.0f / (float)(dfull + 1);
        const int d = min(dfull, CAP);

        uint4 VA[4], VB[4];
        issue4(xb, pre[p], gl, l16, Nn, 0, VA);

        float a[8];
        {
            uint4 o = own[p];
            a[0] = bf2f((unsigned short)(o.x & 0xffff));
            a[1] = bf2f((unsigned short)(o.x >> 16));
            a[2] = bf2f((unsigned short)(o.y & 0xffff));
            a[3] = bf2f((unsigned short)(o.y >> 16));
            a[4] = bf2f((unsigned short)(o.z & 0xffff));
            a[5] = bf2f((unsigned short)(o.z >> 16));
            a[6] = bf2f((unsigned short)(o.w & 0xffff));
            a[7] = bf2f((unsigned short)(o.w >> 16));
        }

        // 2-deep ping-pong: issue round j+4 before consuming round j
        int j = 0;
        while (true) {
            if (j + 4 < d) issue4(xb, pre[p], gl, l16, Nn, j + 4, VB);
            consume4(a, VA, j, d);
            j += 4;
            if (j >= d) break;
            if (j + 4 < d) issue4(xb, pre[p], gl, l16, Nn, j + 4, VA);
            consume4(a, VB, j, d);
            j += 4;
            if (j >= d) break;
        }

#pragma unroll
        for (int i = 0; i < 8; ++i) a[i] *= id;
        uint4 o;
        o.x = (uint32_t)f2bf(a[0]) | ((uint32_t)f2bf(a[1]) << 16);
        o.y = (uint32_t)f2bf(a[2]) | ((uint32_t)f2bf(a[3]) << 16);
        o.z = (uint32_t)f2bf(a[4]) | ((uint32_t)f2bf(a[5]) << 16);
        o.w = (uint32_t)f2bf(a[6]) | ((uint32_t)f2bf(a[7]) << 16);
        int node = row0 + r;
        if (node < Nn)
            *(uint4*)((char*)xout + (size_t)node * 256 + l16 * 16) = o;
    }
}

// ---------------------------------------------------------------------------
// Fused GateMLP + fin_W projection (r12-verified gate recipe; epilogue now
// projects r*g (fp32, in registers) onto fin_W's 10 columns per row via
// per-16-lane-group shfl_xor reduction and writes y[N x 10] fp32 — deletes
// the 25.6MB bf16 store + pool re-read + final_gemm; pool10 finishes.
// First-stage weights: DEEP-FOLDED slots 9/10 (= We W1 W2 W3 W4 {rW1,sW1}).
// ---------------------------------------------------------------------------
__global__ __launch_bounds__(512, 4) void gate_fused(const unsigned short* __restrict__ x,
                                                     const unsigned short* __restrict__ wpack,
                                                     const float* __restrict__ rb1f,
                                                     const float* __restrict__ rb2,
                                                     const float* __restrict__ sb1f,
                                                     const float* __restrict__ sb2,
                                                     const float* __restrict__ finW,
                                                     float* __restrict__ y, int M) {
    __shared__ unsigned short Ws[2 * 128 * 128];   // 64 KB: two weight matrices
    const int tid = threadIdx.x;
    const int lane = tid & 63;
    const int w = tid >> 6;            // wave 0..7
    const int l16 = lane & 15;
    const int fg = lane >> 4;
    const int row0 = blockIdx.x * 128 + w * 16;

    // B-frags of x^T for this wave's 16 rows (direct from global, 16B/lane)
    int xr = row0 + l16;
    if (xr >= M) xr = M - 1;
    short8v xbf[4];
#pragma unroll
    for (int kc = 0; kc < 4; ++kc)
        xbf[kc] = *(const short8v*)(x + (size_t)xr * 128 + kc * 32 + fg * 8);

    const short8v* WL = (const short8v*)Ws;
    uint32_t upR[8][2], upS[8][2];

    union { uint32_t u[4]; short8v v; } cvt;

#define STAGE2(mi0, mi1)                                                      \
    {                                                                         \
        const short8v* s0 = (const short8v*)(wpack + (size_t)(mi0) * 16384);  \
        const short8v* s1 = (const short8v*)(wpack + (size_t)(mi1) * 16384);  \
        short8v* dst = (short8v*)Ws;                                          \
        _Pragma("unroll") for (int i = 0; i < 4; ++i)                         \
            dst[i * 512 + tid] = s0[i * 512 + tid];                          \
        _Pragma("unroll") for (int i = 0; i < 4; ++i)                         \
            dst[2048 + i * 512 + tid] = s1[i * 512 + tid];                    \
    }

#define PASS1(OFS, BIAS, UP)                                                  \
    _Pragma("unroll") for (int nt = 0; nt < 8; ++nt) {                        \
        float4v acc = (float4v){0.f, 0.f, 0.f, 0.f};                          \
        _Pragma("unroll") for (int kc = 0; kc < 4; ++kc)                      \
            acc = __builtin_amdgcn_mfma_f32_16x16x32_bf16(                    \
                WL[(OFS) + (kc * 4 + fg) * 128 + nt * 16 + l16], xbf[kc], acc, 0, 0, 0); \
        _Pragma("unroll") for (int q = 0; q < 4; ++q) {                       \
            float v = acc[q] + (BIAS)[nt * 16 + fg * 4 + q];                  \
            acc[q] = v > 0.f ? v : LEAK * v;                                  \
        }                                                                     \
        UP[nt][0] = (uint32_t)f2bf(acc[0]) | ((uint32_t)f2bf(acc[1]) << 16);  \
        UP[nt][1] = (uint32_t)f2bf(acc[2]) | ((uint32_t)f2bf(acc[3]) << 16);  \
    }

#define MKUF(UP, UF)                                                          \
    _Pragma("unroll") for (int kc = 0; kc < 4; ++kc) {                        \
        uint32_t pr0, pr1, pr2, pr3;                                          \
        {                                                                     \
            int srcl = (((2 * fg + 0) & 3) << 4) + l16;                       \
            uint32_t lo = __shfl((int)UP[2 * kc][0], srcl);                   \
            uint32_t hi = __shfl((int)UP[2 * kc + 1][0], srcl);               \
            pr0 = (fg & 2) ? hi : lo;                                         \
            lo = __shfl((int)UP[2 * kc][1], srcl);                            \
            hi = __shfl((int)UP[2 * kc + 1][1], srcl);                        \
            pr1 = (fg & 2) ? hi : lo;                                         \
        }                                                                     \
        {                                                                     \
            int srcl = (((2 * fg + 1) & 3) << 4) + l16;                       \
            uint32_t lo = __shfl((int)UP[2 * kc][0], srcl);                   \
            uint32_t hi = __shfl((int)UP[2 * kc + 1][0], srcl);               \
            pr2 = (fg & 2) ? hi : lo;                                         \
            lo = __shfl((int)UP[2 * kc][1], srcl);                            \
            hi = __shfl((int)UP[2 * kc + 1][1], srcl);                        \
            pr3 = (fg & 2) ? hi : lo;                                         \
        }                                                                     \
        cvt.u[0] = pr0; cvt.u[1] = pr1; cvt.u[2] = pr2; cvt.u[3] = pr3;       \
        UF[kc] = cvt.v;                                                       \
    }

    // ---- stage 1: deep-folded W1R + W1S (slots 9, 10) ----
    STAGE2(9, 10);
    __syncthreads();
    PASS1(0, rb1f, upR);
    PASS1(2048, sb1f, upS);
    __syncthreads();

    // ---- stage 2: W2R + W2S (slots 6, 8) ----
    STAGE2(6, 8);
    __syncthreads();

    // R pass 2: rf = leaky(u_R @ W_r2 + rb2)
    short8v uf[4];
    MKUF(upR, uf);
    float4v rf[8];
#pragma unroll
    for (int t2 = 0; t2 < 8; ++t2) {
        float4v acc = (float4v){0.f, 0.f, 0.f, 0.f};
#pragma unroll
        for (int kc = 0; kc < 4; ++kc)
            acc = __builtin_amdgcn_mfma_f32_16x16x32_bf16(
                uf[kc], WL[(kc * 4 + fg) * 128 + t2 * 16 + l16], acc, 0, 0, 0);
        const float bv = rb2[t2 * 16 + l16];
#pragma unroll
        for (int q = 0; q < 4; ++q) {
            float v = acc[q] + bv;
            rf[t2][q] = v > 0.f ? v : LEAK * v;
        }
    }

    // S pass 2: rf *= sigmoid(u_S @ W_s2 + sb2)   (r*g kept fp32 in regs)
    MKUF(upS, uf);
#pragma unroll
    for (int t2 = 0; t2 < 8; ++t2) {
        float4v acc = (float4v){0.f, 0.f, 0.f, 0.f};
#pragma unroll
        for (int kc = 0; kc < 4; ++kc)
            acc = __builtin_amdgcn_mfma_f32_16x16x32_bf16(
                uf[kc], WL[2048 + (kc * 4 + fg) * 128 + t2 * 16 + l16], acc, 0, 0, 0);
        const float bv = sb2[t2 * 16 + l16];
#pragma unroll
        for (int q = 0; q < 4; ++q) {
            float gg = 1.f / (1.f + __expf(-(acc[q] + bv)));
            rf[t2][q] *= gg;
        }
    }

    // ---- fin_W projection epilogue: y[row][c] = (r*g row) . finW[:,c] ----
    // row (row0+fg*4+q) cols live as {col = t2*16 + l16} across the 16-lane
    // group; per c: 8 FMA + 4-step shfl_xor reduce (stays within the group).
#pragma unroll 1
    for (int c = 0; c < 10; ++c) {
        float fw[8];
#pragma unroll
        for (int t2 = 0; t2 < 8; ++t2)
            fw[t2] = finW[(size_t)(t2 * 16 + l16) * 10 + c];
#pragma unroll
        for (int q = 0; q < 4; ++q) {
            float p = 0.f;
#pragma unroll
            for (int t2 = 0; t2 < 8; ++t2)
                p = fmaf(rf[t2][q], fw[t2], p);
            p += __shfl_xor(p, 1);
            p += __shfl_xor(p, 2);
            p += __shfl_xor(p, 4);
            p += __shfl_xor(p, 8);
            if (l16 == 0) {
                int row = row0 + fg * 4 + q;
                if (row < M) y[(size_t)row * 10 + c] = p;
            }
        }
    }
#undef STAGE2
#undef PASS1
#undef MKUF
}

// ---------------------------------------------------------------------------
// pool10: out[g][c] = (sum over graph rows of y[.][c]) / cnt_g + fin_b[c].
// One 256-thread block per graph; c = tid&15 (c<10 active), 16 row-groups.
// ---------------------------------------------------------------------------
__global__ void pool10(const float* __restrict__ y, const int* __restrict__ goff,
                       const float* __restrict__ fb, float* __restrict__ out, int G_) {
    __shared__ float sh[16][16];
    int g = blockIdx.x;
    int c = threadIdx.x & 15;
    int rg = threadIdx.x >> 4;
    int a0 = goff[g], a1 = goff[g + 1];
    float s = 0.f;
    if (c < 10)
        for (int r = a0 + rg; r < a1; r += 16)
            s += y[(size_t)r * 10 + c];
    sh[rg][c] = s;
    __syncthreads();
    if (rg == 0 && c < 10) {
        float tot = 0.f;
#pragma unroll
        for (int i = 0; i < 16; ++i) tot += sh[i][c];
        out[(size_t)g * 10 + c] = tot / (float)max(a1 - a0, 1) + fb[c];
    }
}

// ---------------------------------------------------------------------------
extern "C" void kernel_launch(void* const* d_in, const int* in_sizes, int n_in,
                              void* d_out, int out_size, void* d_ws, size_t ws_size,
                              hipStream_t stream) {
    const float* node_attr = (const float*)d_in[0];
    const int* edge_index  = (const int*)d_in[1];
    const int* num_atoms   = (const int*)d_in[2];
    const float* enc_W = (const float*)d_in[3];
    const float* enc_b = (const float*)d_in[4];
    const float* gcn_W = (const float*)d_in[5];
    const float* gcn_b = (const float*)d_in[6];
    const float* r_W1 = (const float*)d_in[7];
    const float* r_b1 = (const float*)d_in[8];
    const float* r_W2 = (const float*)d_in[9];
    const float* r_b2 = (const float*)d_in[10];
    const float* s_W1 = (const float*)d_in[11];
    const float* s_b1 = (const float*)d_in[12];
    const float* s_W2 = (const float*)d_in[13];
    const float* s_b2 = (const float*)d_in[14];
    const float* fin_W = (const float*)d_in[15];
    const float* fin_b = (const float*)d_in[16];
    float* out = (float*)d_out;

    const int N_ = in_sizes[0] / 128;
    const int E_ = in_sizes[1] / 2;
    const int G_ = in_sizes[2];

    size_t off = 0;
    auto alloc = [&](size_t bytes) -> void* {
        void* p = (char*)d_ws + off;
        off += (bytes + 255) & ~(size_t)255;
        return p;
    };
    unsigned short* bx = (unsigned short*)alloc((size_t)N_ * 128 * 2);
    unsigned short* bh = (unsigned short*)alloc((size_t)N_ * 128 * 2);
    int* bucket = (int*)alloc((size_t)N_ * CAP * 4);
    int* cnt    = (int*)alloc((size_t)N_ * 4);
    unsigned short* wpack = (unsigned short*)alloc((size_t)11 * 16384 * 2);
    float* fold32 = (float*)alloc((size_t)5 * 16384 * 4);   // A,B,C,D,E fp32
    float* fbias = (float*)alloc((size_t)3 * 128 * 4);
    float* ybuf = (float*)alloc((size_t)N_ * 10 * 4);
    int* goff   = (int*)alloc((size_t)(G_ + 1) * 4);
    (void)ws_size; (void)n_in; (void)out_size;

    const int agg_grid = (N_ + 63) / 64;
    const int NB_EDGE = (E_ / 8 + 255) / 256;
    const int NB_CVT = (N_ * 16 + 255) / 256;
    const int NB_PREP = NB_EDGE + NB_CVT + 16 + 256 + 2;

    // 1. prep: buckets || convert || pack(6,8) || fold L1 (A,B,C,D) || beta || scan
    hipMemsetAsync(cnt, 0, (size_t)N_ * 4, stream);
    prep<<<NB_PREP, 256, 0, stream>>>(edge_index, E_, cnt, bucket,
                                      node_attr, bx, N_,
                                      enc_W, gcn_W, r_W1, r_W2, s_W1, s_W2,
                                      enc_b, gcn_b, r_b1, s_b1,
                                      wpack, fold32, fbias, num_atoms, goff, G_,
                                      NB_EDGE, NB_CVT);

    // 2. four aggregate-only passes; fold L2 (E=A@B) rides agg1, fold L3
    //    (slots 9/10) rides agg2 as extra low-VGPR blocks (hidden).
    agg_pass<1><<<agg_grid + 64, 256, 0, stream>>>(bx, bucket, cnt, bh, N_,
                                                   agg_grid, fold32, wpack);
    agg_pass<2><<<agg_grid + 128, 256, 0, stream>>>(bh, bucket, cnt, bx, N_,
                                                    agg_grid, fold32, wpack);
    agg_pass<0><<<agg_grid, 256, 0, stream>>>(bx, bucket, cnt, bh, N_,
                                              agg_grid, fold32, wpack);
    agg_pass<0><<<agg_grid, 256, 0, stream>>>(bh, bucket, cnt, bx, N_,
                                              agg_grid, fold32, wpack);

    // 3. gate on aggregated input; epilogue projects onto fin_W -> y[N x 10]
    gate_fused<<<(N_ + 127) / 128, 512, 0, stream>>>(bx, wpack, fbias + 128, r_b2,
                                                     fbias + 256, s_b2, fin_W, ybuf, N_);

    // 4. pool over 10-dim projections + bias
    pool10<<<G_, 256, 0, stream>>>(ybuf, goff, fin_b, out, G_);
}

// Round 19
// 242.029 us; speedup vs baseline: 1.0296x; 1.0296x over previous
//
#include <hip/hip_runtime.h>
#include <hip/hip_bf16.h>
#include <cstddef>
#include <cstdint>

#define CAP 32
#define LEAK 0.01f

typedef __attribute__((ext_vector_type(8))) short short8v;
typedef __attribute__((ext_vector_type(4))) float float4v;

__device__ __forceinline__ unsigned short f2bf(float f) {
    uint32_t u = __float_as_uint(f);
    uint32_t r = (u + 0x7FFFu + ((u >> 16) & 1u)) >> 16;   // RNE
    return (unsigned short)r;
}
__device__ __forceinline__ float bf2f(unsigned short s) {
    return __uint_as_float(((uint32_t)s) << 16);
}

// ---------------------------------------------------------------------------
// prep: one kernel, block-ranges (overlap latency-bound edge atomics with the
// BW-bound convert and tiny pack/fold/scan work). All fold work is plain fp32
// dot products (low VGPR; r16 lesson). Scatter: 8 edges/thread.
// ---------------------------------------------------------------------------
__global__ __launch_bounds__(256) void prep(const int* __restrict__ ei, int E_,
                                            int* __restrict__ cnt,
                                            int* __restrict__ bucket,
                                            const float* __restrict__ node_attr,
                                            unsigned short* __restrict__ bx, int Nn,
                                            const float* __restrict__ enc_W,
                                            const float* __restrict__ gcn_W,
                                            const float* __restrict__ rw1,
                                            const float* __restrict__ rw2,
                                            const float* __restrict__ sw1,
                                            const float* __restrict__ sw2,
                                            const float* __restrict__ enc_b,
                                            const float* __restrict__ gcn_b,
                                            const float* __restrict__ rb1,
                                            const float* __restrict__ sb1,
                                            unsigned short* __restrict__ wpack,
                                            float* __restrict__ fold32,
                                            float* __restrict__ fbias,
                                            const int* __restrict__ na,
                                            int* __restrict__ goff, int G_,
                                            int NB_EDGE, int NB_CVT) {
    const int b = blockIdx.x;
    const int tid = threadIdx.x;

    if (b < NB_EDGE) {
        int e = (b * 256 + tid) * 8;
        if (e >= E_) return;
        if (e + 8 <= E_) {
            int4 da = *(const int4*)&ei[e];
            int4 db = *(const int4*)&ei[e + 4];
            int4 sa = *(const int4*)&ei[(size_t)E_ + e];
            int4 sb = *(const int4*)&ei[(size_t)E_ + e + 4];
            int p0 = atomicAdd(&cnt[da.x], 1);
            int p1 = atomicAdd(&cnt[da.y], 1);
            int p2 = atomicAdd(&cnt[da.z], 1);
            int p3 = atomicAdd(&cnt[da.w], 1);
            int p4 = atomicAdd(&cnt[db.x], 1);
            int p5 = atomicAdd(&cnt[db.y], 1);
            int p6 = atomicAdd(&cnt[db.z], 1);
            int p7 = atomicAdd(&cnt[db.w], 1);
            if (p0 < CAP) bucket[(size_t)da.x * CAP + p0] = sa.x;
            if (p1 < CAP) bucket[(size_t)da.y * CAP + p1] = sa.y;
            if (p2 < CAP) bucket[(size_t)da.z * CAP + p2] = sa.z;
            if (p3 < CAP) bucket[(size_t)da.w * CAP + p3] = sa.w;
            if (p4 < CAP) bucket[(size_t)db.x * CAP + p4] = sb.x;
            if (p5 < CAP) bucket[(size_t)db.y * CAP + p5] = sb.y;
            if (p6 < CAP) bucket[(size_t)db.z * CAP + p6] = sb.z;
            if (p7 < CAP) bucket[(size_t)db.w * CAP + p7] = sb.w;
        } else {
            for (; e < E_; ++e) {
                int d = ei[e], s = ei[(size_t)E_ + e];
                int p = atomicAdd(&cnt[d], 1);
                if (p < CAP) bucket[(size_t)d * CAP + p] = s;
            }
        }
        return;
    }
    if (b < NB_EDGE + NB_CVT) {
        size_t i8 = ((size_t)(b - NB_EDGE) * 256 + tid) * 8;
        if (i8 < (size_t)Nn * 128) {
            const float* ap = node_attr + i8;
            float4v p = *(const float4v*)ap;
            float4v q = *(const float4v*)(ap + 4);
            short8v v;
            v[0] = (short)f2bf(p[0]); v[1] = (short)f2bf(p[1]);
            v[2] = (short)f2bf(p[2]); v[3] = (short)f2bf(p[3]);
            v[4] = (short)f2bf(q[0]); v[5] = (short)f2bf(q[1]);
            v[6] = (short)f2bf(q[2]); v[7] = (short)f2bf(q[3]);
            *(short8v*)(bx + i8) = v;
        }
        return;
    }
    if (b < NB_EDGE + NB_CVT + 16) {
        int pb = b - (NB_EDGE + NB_CVT);
        int m = (pb < 8) ? 6 : 8;
        int idx = (pb & 7) * 256 + tid;
        const float* W = (m == 6) ? rw2 : sw2;
        int n = idx & 127;
        int fg = (idx >> 7) & 3;
        int kc = idx >> 9;
        short8v v;
#pragma unroll
        for (int j = 0; j < 8; ++j)
            v[j] = (short)f2bf(W[(size_t)(kc * 32 + fg * 8 + j) * 128 + n]);
        *(short8v*)(wpack + (size_t)m * 16384 + (size_t)idx * 8) = v;
        return;
    }
    int fb = b - (NB_EDGE + NB_CVT + 16);
    if (fb < 256) {
        // ---- fold level 1: 4 independent 128x128 fp32 products ----
        int which = fb >> 6;                 // 0:A=We@W1 1:B=W2@W3 2:C=W4@rW1 3:D=W4@sW1
        int r = (fb & 63) * 2 + (tid >> 7);  // output row
        int n = tid & 127;                   // output col
        const float* L;
        const float* R;
        switch (which) {
            case 0: L = enc_W;                       R = gcn_W;                 break;
            case 1: L = gcn_W + (size_t)1 * 16384;   R = gcn_W + (size_t)2 * 16384; break;
            case 2: L = gcn_W + (size_t)3 * 16384;   R = rw1;                   break;
            default: L = gcn_W + (size_t)3 * 16384;  R = sw1;                   break;
        }
        float acc = 0.f;
#pragma unroll 8
        for (int k = 0; k < 128; ++k)
            acc = fmaf(L[(size_t)r * 128 + k], R[(size_t)k * 128 + n], acc);
        fold32[(size_t)which * 16384 + (size_t)r * 128 + n] = acc;
        return;
    }
    fb -= 256;
    if (fb == 0) {
        // ---- beta chain + folded biases (fp32 exact) ----
        __shared__ float betaL[128];
        if (tid < 128) betaL[tid] = enc_b[tid];
        __syncthreads();
        for (int l = 0; l < 4; ++l) {
            const float* Wl = gcn_W + (size_t)l * 16384;
            float acc = 0.f;
            if (tid < 128) {
                acc = gcn_b[l * 128 + tid];
                for (int k = 0; k < 128; ++k)
                    acc = fmaf(betaL[k], Wl[(size_t)k * 128 + tid], acc);
            }
            __syncthreads();
            if (tid < 128) betaL[tid] = acc;
            __syncthreads();
        }
        if (tid < 128) {
            float a1 = rb1[tid], a2 = sb1[tid];
            for (int k = 0; k < 128; ++k) {
                float bk = betaL[k];
                a1 = fmaf(bk, rw1[(size_t)k * 128 + tid], a1);
                a2 = fmaf(bk, sw1[(size_t)k * 128 + tid], a2);
            }
            fbias[128 + tid] = a1;
            fbias[256 + tid] = a2;
        }
        return;
    }
    if (fb == 1) {
        // ---- exclusive scan num_atoms -> goff (G <= 1024) ----
        __shared__ int sh[256];
        int base = tid * 4;
        int v0 = (base + 0 < G_) ? na[base + 0] : 0;
        int v1 = (base + 1 < G_) ? na[base + 1] : 0;
        int v2 = (base + 2 < G_) ? na[base + 2] : 0;
        int v3 = (base + 3 < G_) ? na[base + 3] : 0;
        int s = v0 + v1 + v2 + v3;
        sh[tid] = s;
        __syncthreads();
        for (int ofs = 1; ofs < 256; ofs <<= 1) {
            int u = (tid >= ofs) ? sh[tid - ofs] : 0;
            __syncthreads();
            sh[tid] += u;
            __syncthreads();
        }
        int run = sh[tid] - s;
        if (tid == 0) goff[0] = 0;
        run += v0; if (base + 0 < G_) goff[base + 1] = run;
        run += v1; if (base + 1 < G_) goff[base + 2] = run;
        run += v2; if (base + 2 < G_) goff[base + 3] = run;
        run += v3; if (base + 3 < G_) goff[base + 4] = run;
    }
}

// ---------------------------------------------------------------------------
// accumulate 8 bf16 (uint4) into 8 f32, predicated by m
// ---------------------------------------------------------------------------
__device__ __forceinline__ void acc8(float a[8], uint4 v, float m) {
    a[0] = fmaf(m, bf2f((unsigned short)(v.x & 0xffff)), a[0]);
    a[1] = fmaf(m, bf2f((unsigned short)(v.x >> 16)), a[1]);
    a[2] = fmaf(m, bf2f((unsigned short)(v.y & 0xffff)), a[2]);
    a[3] = fmaf(m, bf2f((unsigned short)(v.y >> 16)), a[3]);
    a[4] = fmaf(m, bf2f((unsigned short)(v.z & 0xffff)), a[4]);
    a[5] = fmaf(m, bf2f((unsigned short)(v.z >> 16)), a[5]);
    a[6] = fmaf(m, bf2f((unsigned short)(v.w & 0xffff)), a[6]);
    a[7] = fmaf(m, bf2f((unsigned short)(v.w >> 16)), a[7]);
}

// issue the 4 gather loads for round jb of this group's node into V[0..3]
__device__ __forceinline__ void issue4(const char* __restrict__ xb, int2 prep_,
                                       int gl, int l16, int Nn, int jb, uint4 V[4]) {
    const int sl = gl + (jb >> 1);
    int s0 = __shfl(prep_.x, sl);
    int s1 = __shfl(prep_.y, sl);
    int s2 = __shfl(prep_.x, sl + 1);
    int s3 = __shfl(prep_.y, sl + 1);
    s0 = min(max(s0, 0), Nn - 1);   // masked slots hold poison -> clamp to hot row
    s1 = min(max(s1, 0), Nn - 1);
    s2 = min(max(s2, 0), Nn - 1);
    s3 = min(max(s3, 0), Nn - 1);
    V[0] = *(const uint4*)(xb + (size_t)s0 * 256 + l16 * 16);
    V[1] = *(const uint4*)(xb + (size_t)s1 * 256 + l16 * 16);
    V[2] = *(const uint4*)(xb + (size_t)s2 * 256 + l16 * 16);
    V[3] = *(const uint4*)(xb + (size_t)s3 * 256 + l16 * 16);
}

__device__ __forceinline__ void consume4(float a[8], const uint4 V[4], int jb, int d) {
    acc8(a, V[0], (jb + 0 < d) ? 1.f : 0.f);
    acc8(a, V[1], (jb + 1 < d) ? 1.f : 0.f);
    acc8(a, V[2], (jb + 2 < d) ? 1.f : 0.f);
    acc8(a, V[3], (jb + 3 < d) ? 1.f : 0.f);
}

// ---------------------------------------------------------------------------
// Aggregate-only pass (r12-verified gather structure). All 4 GCN layers are
// pure aggregation (weights folded into the gate via linearity).
// FM = fold-tail mode for blocks >= aggGrid (hidden fold work, low VGPR):
//   FM=0 none; FM=1 E=A@B (fp32, 64 blocks); FM=2 slots 9/10 = E@{C,D}
//   (bf16 fragpack, 128 blocks).
// ---------------------------------------------------------------------------
template <int FM>
__global__ __launch_bounds__(256, 4) void agg_pass(const unsigned short* __restrict__ x,
                                                   const int* __restrict__ bucket,
                                                   const int* __restrict__ cnt,
                                                   unsigned short* __restrict__ xout,
                                                   int Nn, int aggGrid,
                                                   float* __restrict__ fold32,
                                                   unsigned short* __restrict__ wpack) {
    if (FM != 0 && (int)blockIdx.x >= aggGrid) {
        const int tid = threadIdx.x;
        const int e = blockIdx.x - aggGrid;
        if (FM == 1) {
            // E = A @ B
            int r = e * 2 + (tid >> 7), n = tid & 127;
            const float* A = fold32;
            const float* B = fold32 + 16384;
            float acc = 0.f;
#pragma unroll 8
            for (int k = 0; k < 128; ++k)
                acc = fmaf(A[(size_t)r * 128 + k], B[(size_t)k * 128 + n], acc);
            fold32[65536 + (size_t)r * 128 + n] = acc;
        } else {
            // slot9 = E @ C ; slot10 = E @ D  (bf16 fragpack layout)
            int panel = e >> 6;
            int r = (e & 63) * 2 + (tid >> 7), n = tid & 127;
            const float* Ep = fold32 + 65536;
            const float* CD = fold32 + (size_t)(2 + panel) * 16384;
            float acc = 0.f;
#pragma unroll 8
            for (int k = 0; k < 128; ++k)
                acc = fmaf(Ep[(size_t)r * 128 + k], CD[(size_t)k * 128 + n], acc);
            int kc = r >> 5, fg2 = (r >> 3) & 3, j = r & 7;
            wpack[(size_t)(9 + panel) * 16384 +
                  (size_t)(((kc * 4 + fg2) * 128 + n) * 8 + j)] = f2bf(acc);
        }
        return;
    }

    const int tid = threadIdx.x;
    const int lane = tid & 63;
    const int w = tid >> 6;
    const int row0 = blockIdx.x * 64;
    const int l16 = lane & 15;
    const int g = lane >> 4;          // 16-lane group 0..3
    const int gl = lane & 48;         // g*16
    const char* xb = (const char*)x;

    // ---- up-front prefetch: cnt (1 load), own rows (4), neighbor idx (4) ----
    int cfull = 0;
    if (lane < 16) {
        int gn = row0 + w * 16 + lane;
        if (gn >= Nn) gn = Nn - 1;
        cfull = cnt[gn];
    }
    uint4 own[4];
    int2 pre[4];      // pass p: slots 2*l16, 2*l16+1 of node 4p+g (covers 0..31)
#pragma unroll
    for (int p = 0; p < 4; ++p) {
        int gn = row0 + w * 16 + p * 4 + g;
        if (gn >= Nn) gn = Nn - 1;
        own[p] = *(const uint4*)(xb + (size_t)gn * 256 + l16 * 16);
        pre[p] = *(const int2*)&bucket[(size_t)gn * CAP + 2 * l16];
    }

    // ---- 4 gather passes, fully unrolled (static own/pre indexing) ----
#pragma unroll
    for (int p = 0; p < 4; ++p) {
        const int n = p * 4 + g;          // node within wave tile, 0..15
        const int r = w * 16 + n;
        const int dfull = __shfl(cfull, n);
        const float id = 1.0f / (float)(dfull + 1);
        const int d = min(dfull, CAP);

        uint4 VA[4], VB[4];
        issue4(xb, pre[p], gl, l16, Nn, 0, VA);

        float a[8];
        {
            uint4 o = own[p];
            a[0] = bf2f((unsigned short)(o.x & 0xffff));
            a[1] = bf2f((unsigned short)(o.x >> 16));
            a[2] = bf2f((unsigned short)(o.y & 0xffff));
            a[3] = bf2f((unsigned short)(o.y >> 16));
            a[4] = bf2f((unsigned short)(o.z & 0xffff));
            a[5] = bf2f((unsigned short)(o.z >> 16));
            a[6] = bf2f((unsigned short)(o.w & 0xffff));
            a[7] = bf2f((unsigned short)(o.w >> 16));
        }

        // 2-deep ping-pong: issue round j+4 before consuming round j
        int j = 0;
        while (true) {
            if (j + 4 < d) issue4(xb, pre[p], gl, l16, Nn, j + 4, VB);
            consume4(a, VA, j, d);
            j += 4;
            if (j >= d) break;
            if (j + 4 < d) issue4(xb, pre[p], gl, l16, Nn, j + 4, VA);
            consume4(a, VB, j, d);
            j += 4;
            if (j >= d) break;
        }

#pragma unroll
        for (int i = 0; i < 8; ++i) a[i] *= id;
        uint4 o;
        o.x = (uint32_t)f2bf(a[0]) | ((uint32_t)f2bf(a[1]) << 16);
        o.y = (uint32_t)f2bf(a[2]) | ((uint32_t)f2bf(a[3]) << 16);
        o.z = (uint32_t)f2bf(a[4]) | ((uint32_t)f2bf(a[5]) << 16);
        o.w = (uint32_t)f2bf(a[6]) | ((uint32_t)f2bf(a[7]) << 16);
        int node = row0 + r;
        if (node < Nn)
            *(uint4*)((char*)xout + (size_t)node * 256 + l16 * 16) = o;
    }
}

// ---------------------------------------------------------------------------
// Fused GateMLP + fin_W projection. r18 post-mortem: the projection's 80
// uncoalesced scalar finW loads per thread were the cost — now finW is staged
// TRANSPOSED into the (dead-after-MFMA) Ws LDS and read as conflict-free
// broadcasts. Everything up to the epilogue is the r12-verified recipe with
// deep-folded first-stage weights (slots 9/10).
// ---------------------------------------------------------------------------
__global__ __launch_bounds__(512, 4) void gate_fused(const unsigned short* __restrict__ x,
                                                     const unsigned short* __restrict__ wpack,
                                                     const float* __restrict__ rb1f,
                                                     const float* __restrict__ rb2,
                                                     const float* __restrict__ sb1f,
                                                     const float* __restrict__ sb2,
                                                     const float* __restrict__ finW,
                                                     float* __restrict__ y, int M) {
    __shared__ unsigned short Ws[2 * 128 * 128];   // 64 KB: two weight matrices
    const int tid = threadIdx.x;
    const int lane = tid & 63;
    const int w = tid >> 6;            // wave 0..7
    const int l16 = lane & 15;
    const int fg = lane >> 4;
    const int row0 = blockIdx.x * 128 + w * 16;

    // B-frags of x^T for this wave's 16 rows (direct from global, 16B/lane)
    int xr = row0 + l16;
    if (xr >= M) xr = M - 1;
    short8v xbf[4];
#pragma unroll
    for (int kc = 0; kc < 4; ++kc)
        xbf[kc] = *(const short8v*)(x + (size_t)xr * 128 + kc * 32 + fg * 8);

    const short8v* WL = (const short8v*)Ws;
    uint32_t upR[8][2], upS[8][2];

    union { uint32_t u[4]; short8v v; } cvt;

#define STAGE2(mi0, mi1)                                                      \
    {                                                                         \
        const short8v* s0 = (const short8v*)(wpack + (size_t)(mi0) * 16384);  \
        const short8v* s1 = (const short8v*)(wpack + (size_t)(mi1) * 16384);  \
        short8v* dst = (short8v*)Ws;                                          \
        _Pragma("unroll") for (int i = 0; i < 4; ++i)                         \
            dst[i * 512 + tid] = s0[i * 512 + tid];                          \
        _Pragma("unroll") for (int i = 0; i < 4; ++i)                         \
            dst[2048 + i * 512 + tid] = s1[i * 512 + tid];                    \
    }

#define PASS1(OFS, BIAS, UP)                                                  \
    _Pragma("unroll") for (int nt = 0; nt < 8; ++nt) {                        \
        float4v acc = (float4v){0.f, 0.f, 0.f, 0.f};                          \
        _Pragma("unroll") for (int kc = 0; kc < 4; ++kc)                      \
            acc = __builtin_amdgcn_mfma_f32_16x16x32_bf16(                    \
                WL[(OFS) + (kc * 4 + fg) * 128 + nt * 16 + l16], xbf[kc], acc, 0, 0, 0); \
        _Pragma("unroll") for (int q = 0; q < 4; ++q) {                       \
            float v = acc[q] + (BIAS)[nt * 16 + fg * 4 + q];                  \
            acc[q] = v > 0.f ? v : LEAK * v;                                  \
        }                                                                     \
        UP[nt][0] = (uint32_t)f2bf(acc[0]) | ((uint32_t)f2bf(acc[1]) << 16);  \
        UP[nt][1] = (uint32_t)f2bf(acc[2]) | ((uint32_t)f2bf(acc[3]) << 16);  \
    }

#define MKUF(UP, UF)                                                          \
    _Pragma("unroll") for (int kc = 0; kc < 4; ++kc) {                        \
        uint32_t pr0, pr1, pr2, pr3;                                          \
        {                                                                     \
            int srcl = (((2 * fg + 0) & 3) << 4) + l16;                       \
            uint32_t lo = __shfl((int)UP[2 * kc][0], srcl);                   \
            uint32_t hi = __shfl((int)UP[2 * kc + 1][0], srcl);               \
            pr0 = (fg & 2) ? hi : lo;                                         \
            lo = __shfl((int)UP[2 * kc][1], srcl);                            \
            hi = __shfl((int)UP[2 * kc + 1][1], srcl);                        \
            pr1 = (fg & 2) ? hi : lo;                                         \
        }                                                                     \
        {                                                                     \
            int srcl = (((2 * fg + 1) & 3) << 4) + l16;                       \
            uint32_t lo = __shfl((int)UP[2 * kc][0], srcl);                   \
            uint32_t hi = __shfl((int)UP[2 * kc + 1][0], srcl);               \
            pr2 = (fg & 2) ? hi : lo;                                         \
            lo = __shfl((int)UP[2 * kc][1], srcl);                            \
            hi = __shfl((int)UP[2 * kc + 1][1], srcl);                        \
            pr3 = (fg & 2) ? hi : lo;                                         \
        }                                                                     \
        cvt.u[0] = pr0; cvt.u[1] = pr1; cvt.u[2] = pr2; cvt.u[3] = pr3;       \
        UF[kc] = cvt.v;                                                       \
    }

    // ---- stage 1: deep-folded W1R + W1S (slots 9, 10) ----
    STAGE2(9, 10);
    __syncthreads();
    PASS1(0, rb1f, upR);
    PASS1(2048, sb1f, upS);
    __syncthreads();

    // ---- stage 2: W2R + W2S (slots 6, 8) ----
    STAGE2(6, 8);
    __syncthreads();

    // R pass 2: rf = leaky(u_R @ W_r2 + rb2)
    short8v uf[4];
    MKUF(upR, uf);
    float4v rf[8];
#pragma unroll
    for (int t2 = 0; t2 < 8; ++t2) {
        float4v acc = (float4v){0.f, 0.f, 0.f, 0.f};
#pragma unroll
        for (int kc = 0; kc < 4; ++kc)
            acc = __builtin_amdgcn_mfma_f32_16x16x32_bf16(
                uf[kc], WL[(kc * 4 + fg) * 128 + t2 * 16 + l16], acc, 0, 0, 0);
        const float bv = rb2[t2 * 16 + l16];
#pragma unroll
        for (int q = 0; q < 4; ++q) {
            float v = acc[q] + bv;
            rf[t2][q] = v > 0.f ? v : LEAK * v;
        }
    }

    // S pass 2: rf *= sigmoid(u_S @ W_s2 + sb2)   (r*g kept fp32 in regs)
    MKUF(upS, uf);
#pragma unroll
    for (int t2 = 0; t2 < 8; ++t2) {
        float4v acc = (float4v){0.f, 0.f, 0.f, 0.f};
#pragma unroll
        for (int kc = 0; kc < 4; ++kc)
            acc = __builtin_amdgcn_mfma_f32_16x16x32_bf16(
                uf[kc], WL[2048 + (kc * 4 + fg) * 128 + t2 * 16 + l16], acc, 0, 0, 0);
        const float bv = sb2[t2 * 16 + l16];
#pragma unroll
        for (int q = 0; q < 4; ++q) {
            float gg = 1.f / (1.f + __expf(-(acc[q] + bv)));
            rf[t2][q] *= gg;
        }
    }

    // ---- stage finW TRANSPOSED into (now dead) Ws LDS: fwL[c][col] ----
    __syncthreads();                       // all MFMA reads of Ws done
    float* fwL = (float*)Ws;               // 10 x 128 fp32 = 5 KB
    for (int idx = tid; idx < 1280; idx += 512) {
        int c = idx >> 7, col = idx & 127;
        fwL[idx] = finW[(size_t)col * 10 + c];
    }
    __syncthreads();

    // ---- fin_W projection epilogue: y[row][c] = (r*g row) . finW[:,c] ----
    // per c: 8 broadcast LDS reads into regs, then per q: 8 FMA + 4 shfl_xor.
#pragma unroll 1
    for (int c = 0; c < 10; ++c) {
        float fw[8];
#pragma unroll
        for (int t2 = 0; t2 < 8; ++t2)
            fw[t2] = fwL[c * 128 + t2 * 16 + l16];
#pragma unroll
        for (int q = 0; q < 4; ++q) {
            float p = 0.f;
#pragma unroll
            for (int t2 = 0; t2 < 8; ++t2)
                p = fmaf(rf[t2][q], fw[t2], p);
            p += __shfl_xor(p, 1);
            p += __shfl_xor(p, 2);
            p += __shfl_xor(p, 4);
            p += __shfl_xor(p, 8);
            if (l16 == 0) {
                int row = row0 + fg * 4 + q;
                if (row < M) y[(size_t)row * 10 + c] = p;
            }
        }
    }
#undef STAGE2
#undef PASS1
#undef MKUF
}

// ---------------------------------------------------------------------------
// pool10: out[g][c] = (sum over graph rows of y[.][c]) / cnt_g + fin_b[c].
// One 256-thread block per graph; c = tid&15 (c<10 active), 16 row-groups.
// ---------------------------------------------------------------------------
__global__ void pool10(const float* __restrict__ y, const int* __restrict__ goff,
                       const float* __restrict__ fb, float* __restrict__ out, int G_) {
    __shared__ float sh[16][16];
    int g = blockIdx.x;
    int c = threadIdx.x & 15;
    int rg = threadIdx.x >> 4;
    int a0 = goff[g], a1 = goff[g + 1];
    float s = 0.f;
    if (c < 10)
        for (int r = a0 + rg; r < a1; r += 16)
            s += y[(size_t)r * 10 + c];
    sh[rg][c] = s;
    __syncthreads();
    if (rg == 0 && c < 10) {
        float tot = 0.f;
#pragma unroll
        for (int i = 0; i < 16; ++i) tot += sh[i][c];
        out[(size_t)g * 10 + c] = tot / (float)max(a1 - a0, 1) + fb[c];
    }
}

// ---------------------------------------------------------------------------
extern "C" void kernel_launch(void* const* d_in, const int* in_sizes, int n_in,
                              void* d_out, int out_size, void* d_ws, size_t ws_size,
                              hipStream_t stream) {
    const float* node_attr = (const float*)d_in[0];
    const int* edge_index  = (const int*)d_in[1];
    const int* num_atoms   = (const int*)d_in[2];
    const float* enc_W = (const float*)d_in[3];
    const float* enc_b = (const float*)d_in[4];
    const float* gcn_W = (const float*)d_in[5];
    const float* gcn_b = (const float*)d_in[6];
    const float* r_W1 = (const float*)d_in[7];
    const float* r_b1 = (const float*)d_in[8];
    const float* r_W2 = (const float*)d_in[9];
    const float* r_b2 = (const float*)d_in[10];
    const float* s_W1 = (const float*)d_in[11];
    const float* s_b1 = (const float*)d_in[12];
    const float* s_W2 = (const float*)d_in[13];
    const float* s_b2 = (const float*)d_in[14];
    const float* fin_W = (const float*)d_in[15];
    const float* fin_b = (const float*)d_in[16];
    float* out = (float*)d_out;

    const int N_ = in_sizes[0] / 128;
    const int E_ = in_sizes[1] / 2;
    const int G_ = in_sizes[2];

    size_t off = 0;
    auto alloc = [&](size_t bytes) -> void* {
        void* p = (char*)d_ws + off;
        off += (bytes + 255) & ~(size_t)255;
        return p;
    };
    unsigned short* bx = (unsigned short*)alloc((size_t)N_ * 128 * 2);
    unsigned short* bh = (unsigned short*)alloc((size_t)N_ * 128 * 2);
    int* bucket = (int*)alloc((size_t)N_ * CAP * 4);
    int* cnt    = (int*)alloc((size_t)N_ * 4);
    unsigned short* wpack = (unsigned short*)alloc((size_t)11 * 16384 * 2);
    float* fold32 = (float*)alloc((size_t)5 * 16384 * 4);   // A,B,C,D,E fp32
    float* fbias = (float*)alloc((size_t)3 * 128 * 4);
    float* ybuf = (float*)alloc((size_t)N_ * 10 * 4);
    int* goff   = (int*)alloc((size_t)(G_ + 1) * 4);
    (void)ws_size; (void)n_in; (void)out_size;

    const int agg_grid = (N_ + 63) / 64;
    const int NB_EDGE = (E_ / 8 + 255) / 256;
    const int NB_CVT = (N_ * 16 + 255) / 256;
    const int NB_PREP = NB_EDGE + NB_CVT + 16 + 256 + 2;

    // 1. prep: buckets || convert || pack(6,8) || fold L1 (A,B,C,D) || beta || scan
    hipMemsetAsync(cnt, 0, (size_t)N_ * 4, stream);
    prep<<<NB_PREP, 256, 0, stream>>>(edge_index, E_, cnt, bucket,
                                      node_attr, bx, N_,
                                      enc_W, gcn_W, r_W1, r_W2, s_W1, s_W2,
                                      enc_b, gcn_b, r_b1, s_b1,
                                      wpack, fold32, fbias, num_atoms, goff, G_,
                                      NB_EDGE, NB_CVT);

    // 2. four aggregate-only passes; fold L2 (E=A@B) rides agg1, fold L3
    //    (slots 9/10) rides agg2 as extra low-VGPR blocks (hidden).
    agg_pass<1><<<agg_grid + 64, 256, 0, stream>>>(bx, bucket, cnt, bh, N_,
                                                   agg_grid, fold32, wpack);
    agg_pass<2><<<agg_grid + 128, 256, 0, stream>>>(bh, bucket, cnt, bx, N_,
                                                    agg_grid, fold32, wpack);
    agg_pass<0><<<agg_grid, 256, 0, stream>>>(bx, bucket, cnt, bh, N_,
                                              agg_grid, fold32, wpack);
    agg_pass<0><<<agg_grid, 256, 0, stream>>>(bh, bucket, cnt, bx, N_,
                                              agg_grid, fold32, wpack);

    // 3. gate on aggregated input; epilogue projects onto fin_W -> y[N x 10]
    gate_fused<<<(N_ + 127) / 128, 512, 0, stream>>>(bx, wpack, fbias + 128, r_b2,
                                                     fbias + 256, s_b2, fin_W, ybuf, N_);

    // 4. pool over 10-dim projections + bias
    pool10<<<G_, 256, 0, stream>>>(ybuf, goff, fin_b, out, G_);
}